// Round 5
// baseline (1502.021 us; speedup 1.0000x reference)
//
#include <hip/hip_runtime.h>
#include <hip/hip_bf16.h>

#define B_ 16
#define S_ 80
#define D_ 512
#define H_ 64
#define DI_ 2048
#define L_ 6
#define G4H 256            // 4*H
#define NROW (B_ * S_)     // 1280 rows = (b, s)
#define EPS_ 1e-6f

typedef __attribute__((ext_vector_type(8))) short short8;
typedef __attribute__((ext_vector_type(4))) float f32x4;

// ---------------- math helpers ----------------
__device__ __forceinline__ float sigmoidf_(float x) {
    return __fdividef(1.0f, 1.0f + __expf(-x));
}
__device__ __forceinline__ float tanh_(float x) {
    return __fdividef(2.0f, 1.0f + __expf(-2.0f * x)) - 1.0f;
}
__device__ __forceinline__ short f2bf(float f) {
    __hip_bfloat16 h = __float2bfloat16(f);   // RNE
    return *reinterpret_cast<short*>(&h);
}

// ---------------- LayerNorm: one block per row, D=512, 256 threads; bf16 out ----------------
__global__ __launch_bounds__(256)
void ln_kernel(const float* __restrict__ x, const float* __restrict__ g,
               const float* __restrict__ b, __hip_bfloat16* __restrict__ out) {
    int row = blockIdx.x;
    int t = threadIdx.x;
    const float* xr = x + (size_t)row * D_;
    float v0 = xr[t], v1 = xr[t + 256];
    __shared__ float red[256];
    red[t] = v0 + v1;
    __syncthreads();
    for (int o = 128; o > 0; o >>= 1) { if (t < o) red[t] += red[t + o]; __syncthreads(); }
    float m = red[0] * (1.0f / (float)D_);
    __syncthreads();
    float d0 = v0 - m, d1 = v1 - m;
    red[t] = d0 * d0 + d1 * d1;
    __syncthreads();
    for (int o = 128; o > 0; o >>= 1) { if (t < o) red[t] += red[t + o]; __syncthreads(); }
    float rs = rsqrtf(red[0] * (1.0f / (float)D_) + EPS_);
    __hip_bfloat16* orow = out + (size_t)row * D_;
    orow[t]       = __float2bfloat16(d0 * rs * g[t]       + b[t]);
    orow[t + 256] = __float2bfloat16(d1 * rs * g[t + 256] + b[t + 256]);
}

// ---------------- bf16 MFMA GEMM: C[M,N] = A[M,K] @ W[N,K]^T (+bias)(+relu)(+res) -----------
// OUT_MODE: 0 = fp32 row-major, 1 = bf16 row-major,
//           2 = fp32 xg3 layout [s][col'][16b] with col' = (4*(u>>4)+gate)*16 + (u&15)
template<int WITH_BIAS, int WITH_RELU, int WITH_RES, int OUT_MODE>
__global__ __launch_bounds__(256)
void mfma_gemm(const __hip_bfloat16* __restrict__ A, const float* __restrict__ W,
               const float* __restrict__ bias, const float* __restrict__ res,
               void* __restrict__ C, int M, int N, int K) {
    const int LDT = 40;  // LDS row stride in bf16 elems
    __shared__ short As[64 * LDT];
    __shared__ short Ws[64 * LDT];

    int tid  = threadIdx.x;
    int wave = tid >> 6, lane = tid & 63;
    int quad = lane >> 4, l16 = lane & 15;
    int m_off = (wave >> 1) * 32, n_off = (wave & 1) * 32;
    int m0 = blockIdx.y * 64, n0 = blockIdx.x * 64;

    int r = tid >> 2, c = tid & 3;           // staging: row 0..63, 8-elem chunk 0..3
    const short* Ag = reinterpret_cast<const short*>(A);

    f32x4 acc00 = {0.f,0.f,0.f,0.f}, acc01 = acc00, acc10 = acc00, acc11 = acc00;

    for (int k0 = 0; k0 < K; k0 += 32) {
        short8 av = *reinterpret_cast<const short8*>(&Ag[(size_t)(m0 + r) * K + k0 + c * 8]);
        const float* wrow = &W[(size_t)(n0 + r) * K + k0 + c * 8];
        float4 w0 = *reinterpret_cast<const float4*>(wrow);
        float4 w1 = *reinterpret_cast<const float4*>(wrow + 4);
        short8 wv;
        wv[0] = f2bf(w0.x); wv[1] = f2bf(w0.y); wv[2] = f2bf(w0.z); wv[3] = f2bf(w0.w);
        wv[4] = f2bf(w1.x); wv[5] = f2bf(w1.y); wv[6] = f2bf(w1.z); wv[7] = f2bf(w1.w);

        __syncthreads();
        *reinterpret_cast<short8*>(&As[r * LDT + c * 8]) = av;
        *reinterpret_cast<short8*>(&Ws[r * LDT + c * 8]) = wv;
        __syncthreads();

        short8 a0 = *reinterpret_cast<const short8*>(&As[(m_off + l16) * LDT + quad * 8]);
        short8 a1 = *reinterpret_cast<const short8*>(&As[(m_off + 16 + l16) * LDT + quad * 8]);
        short8 b0 = *reinterpret_cast<const short8*>(&Ws[(n_off + l16) * LDT + quad * 8]);
        short8 b1 = *reinterpret_cast<const short8*>(&Ws[(n_off + 16 + l16) * LDT + quad * 8]);

        acc00 = __builtin_amdgcn_mfma_f32_16x16x32_bf16(a0, b0, acc00, 0, 0, 0);
        acc01 = __builtin_amdgcn_mfma_f32_16x16x32_bf16(a0, b1, acc01, 0, 0, 0);
        acc10 = __builtin_amdgcn_mfma_f32_16x16x32_bf16(a1, b0, acc10, 0, 0, 0);
        acc11 = __builtin_amdgcn_mfma_f32_16x16x32_bf16(a1, b1, acc11, 0, 0, 0);
    }

    f32x4 accs[2][2] = {{acc00, acc01}, {acc10, acc11}};
    #pragma unroll
    for (int fi = 0; fi < 2; fi++) {
        #pragma unroll
        for (int fj = 0; fj < 2; fj++) {
            int coln = n0 + n_off + fj * 16 + l16;
            float bv = WITH_BIAS ? bias[coln] : 0.0f;
            #pragma unroll
            for (int rr = 0; rr < 4; rr++) {
                int rowm = m0 + m_off + fi * 16 + quad * 4 + rr;
                float v = accs[fi][fj][rr];
                if (WITH_BIAS) v += bv;
                if (WITH_RELU) v = fmaxf(v, 0.0f);
                if (WITH_RES)  v += res[(size_t)rowm * N + coln];
                if (OUT_MODE == 0) {
                    reinterpret_cast<float*>(C)[(size_t)rowm * N + coln] = v;
                } else if (OUT_MODE == 1) {
                    reinterpret_cast<__hip_bfloat16*>(C)[(size_t)rowm * N + coln] = __float2bfloat16(v);
                } else {
                    // xg3[s][col'][16b]; rows m = b*S + s, cols n = gate*64 + u
                    int b_ = rowm / S_;
                    int s_ = rowm - b_ * S_;
                    int gate = coln >> 6, u = coln & 63;
                    int cp = ((u >> 4) * 4 + gate) * 16 + (u & 15);
                    reinterpret_cast<float*>(C)[(((size_t)(s_ * 256 + cp)) << 4) + b_] = v;
                }
            }
        }
    }
}

// ---------------- single-wave MFMA LSTM (no barriers) ----------------
// Grid (80, 2): one 64-thread wave per (output position i, batch half bh).
// The wave owns M=8 sequences placed at MFMA C-rows {0,1,4,5,8,9,12,13}
// (seq p -> row (p>>1)*4 + (p&1)), so every lane holds r=0,1 real rows of each
// acc tile -> 8 (seq,unit) states/lane, evenly spread, no shuffles.
// Tiles t = kb*4 + gate, col' = t*16 + l16 <-> original gate column gate*64+kb*16+l16:
// lane (quad,l16) gets i,f,g,o of (seq quad*2+r, unit kb*16+l16) in acc[kb*4+0..3][r].
// Per step: 2 ds_read_b128 (h) -> 32 MFMA -> lane-local nonlinearity -> 8 ds_write_b16.
// No __syncthreads anywhere: single wave, in-order LDS ops. xg prefetched 1 step ahead
// as 16 coalesced dwordx2 loads (no barrier => no vmcnt(0) drain on the chain).
__global__ __launch_bounds__(64)
void lstm_wave_kernel(const float* __restrict__ xg3,   // [S][256][16] fp32
                      const float* __restrict__ whh,   // [4H, H] fp32
                      __hip_bfloat16* __restrict__ hlast) {  // [B, S, H]
    const int i    = blockIdx.x;      // output position 0..79
    const int bh   = blockIdx.y;      // batch half 0..1
    const int lane = threadIdx.x;
    const int quad = lane >> 4, l16 = lane & 15;

    // B-fragments of whh (bf16), one-time: tile t = kb*4+gate, column n=l16 of the
    // tile <-> whh row gate*64 + kb*16 + l16; k-elements kc*32 + quad*8 + j.
    short8 bf[16][2];
    #pragma unroll
    for (int t = 0; t < 16; t++) {
        int kb = t >> 2, gate = t & 3;
        const float* wr = &whh[(size_t)(gate * 64 + kb * 16 + l16) * H_];
        #pragma unroll
        for (int kc = 0; kc < 2; kc++) {
            float4 x0 = *(const float4*)(wr + kc * 32 + quad * 8);
            float4 x1 = *(const float4*)(wr + kc * 32 + quad * 8 + 4);
            short8 v;
            v[0] = f2bf(x0.x); v[1] = f2bf(x0.y); v[2] = f2bf(x0.z); v[3] = f2bf(x0.w);
            v[4] = f2bf(x1.x); v[5] = f2bf(x1.y); v[6] = f2bf(x1.z); v[7] = f2bf(x1.w);
            bf[t][kc] = v;
        }
    }

    // h tile in LDS: 16 rows (8 real, rest stay zero) x 72 bf16 (144B rows, 16B-aligned)
    __shared__ __attribute__((aligned(16))) short hsh[16][72];
    for (int idx = lane; idx < 16 * 72; idx += 64)
        reinterpret_cast<short*>(hsh)[idx] = 0;

    float cst[4][2] = {};   // c state: [kb][r]
    float hv[4][2];         // last h (for epilogue)

    // xg prefetch: lane's float2 covers seqs p = quad*2 + {0,1} of this batch half
    const int bslot = bh * 8 + quad * 2;
    float2 xgp[16];
    {
        int s0 = (0 == i) ? (S_ - 1) : 0;
        #pragma unroll
        for (int t = 0; t < 16; t++)
            xgp[t] = *reinterpret_cast<const float2*>(
                &xg3[(((size_t)(s0 * 256 + t * 16 + l16)) << 4) + bslot]);
    }

    for (int ts = 0; ts < S_; ts++) {
        // h_{t-1} A-fragments (zeros on first step)
        short8 af0 = *reinterpret_cast<const short8*>(&hsh[l16][quad * 8]);
        short8 af1 = *reinterpret_cast<const short8*>(&hsh[l16][32 + quad * 8]);

        f32x4 acc[16];
        #pragma unroll
        for (int t = 0; t < 16; t++) {
            f32x4 a = {xgp[t].x, xgp[t].y, 0.f, 0.f};
            acc[t] = a;
        }
        #pragma unroll
        for (int t = 0; t < 16; t++) {
            acc[t] = __builtin_amdgcn_mfma_f32_16x16x32_bf16(af0, bf[t][0], acc[t], 0, 0, 0);
            acc[t] = __builtin_amdgcn_mfma_f32_16x16x32_bf16(af1, bf[t][1], acc[t], 0, 0, 0);
        }

        // prefetch next step's xg (consumed next iteration; latency hidden, no barrier)
        if (ts + 1 < S_) {
            int tn = ts + 1;
            int sn = (tn == i) ? (S_ - 1) : ((tn == S_ - 1) ? i : tn);
            #pragma unroll
            for (int t = 0; t < 16; t++)
                xgp[t] = *reinterpret_cast<const float2*>(
                    &xg3[(((size_t)(sn * 256 + t * 16 + l16)) << 4) + bslot]);
        }

        // lane-local nonlinearity: 8 states (kb 0..3, r 0..1), then publish h to LDS
        #pragma unroll
        for (int kb = 0; kb < 4; kb++) {
            #pragma unroll
            for (int r = 0; r < 2; r++) {
                float ig = sigmoidf_(acc[kb * 4 + 0][r]);
                float fg = sigmoidf_(acc[kb * 4 + 1][r]);
                float gg = tanh_(acc[kb * 4 + 2][r]);
                float og = sigmoidf_(acc[kb * 4 + 3][r]);
                float cc = fg * cst[kb][r] + ig * gg;
                cst[kb][r] = cc;
                float h = og * tanh_(cc);
                hv[kb][r] = h;
                hsh[quad * 4 + r][kb * 16 + l16] = f2bf(h);  // row (p>>1)*4+(p&1)
            }
        }
    }

    // epilogue: lane's states are (seq b = bh*8 + quad*2 + r, unit kb*16 + l16)
    #pragma unroll
    for (int kb = 0; kb < 4; kb++)
        #pragma unroll
        for (int r = 0; r < 2; r++) {
            int b = bh * 8 + quad * 2 + r;
            hlast[((size_t)b * S_ + i) * H_ + kb * 16 + l16] = __float2bfloat16(hv[kb][r]);
        }
}

// ---------------- final LN + projection to one logit per row ----------------
__global__ __launch_bounds__(256)
void final_kernel(const float* __restrict__ x, const float* __restrict__ g,
                  const float* __restrict__ b, const float* __restrict__ wprj,
                  float* __restrict__ out) {
    int row = blockIdx.x;
    int t = threadIdx.x;
    const float* xr = x + (size_t)row * D_;
    float v0 = xr[t], v1 = xr[t + 256];
    __shared__ float red[256];
    red[t] = v0 + v1;
    __syncthreads();
    for (int o = 128; o > 0; o >>= 1) { if (t < o) red[t] += red[t + o]; __syncthreads(); }
    float m = red[0] * (1.0f / (float)D_);
    __syncthreads();
    float d0 = v0 - m, d1 = v1 - m;
    red[t] = d0 * d0 + d1 * d1;
    __syncthreads();
    for (int o = 128; o > 0; o >>= 1) { if (t < o) red[t] += red[t + o]; __syncthreads(); }
    float rs = rsqrtf(red[0] * (1.0f / (float)D_) + EPS_);
    __syncthreads();
    float y0 = (d0 * rs * g[t] + b[t]) * wprj[t];
    float y1 = (d1 * rs * g[t + 256] + b[t + 256]) * wprj[t + 256];
    red[t] = y0 + y1;
    __syncthreads();
    for (int o = 128; o > 0; o >>= 1) { if (t < o) red[t] += red[t + o]; __syncthreads(); }
    if (t == 0) out[row] = red[0];
}

// ---------------- host ----------------
extern "C" void kernel_launch(void* const* d_in, const int* in_sizes, int n_in,
                              void* d_out, int out_size, void* d_ws, size_t ws_size,
                              hipStream_t stream) {
    const float* src   = (const float*)d_in[0];
    const float* ln1_g = (const float*)d_in[2];
    const float* ln1_b = (const float*)d_in[3];
    const float* wih   = (const float*)d_in[4];   // [L, 4H, D]
    const float* whh   = (const float*)d_in[5];   // [L, 4H, H]
    const float* wfc   = (const float*)d_in[6];   // [L, D, H]
    const float* ln2_g = (const float*)d_in[7];
    const float* ln2_b = (const float*)d_in[8];
    const float* w1    = (const float*)d_in[9];   // [L, DI, D]
    const float* b1    = (const float*)d_in[10];  // [L, DI]
    const float* w2    = (const float*)d_in[11];  // [L, D, DI]
    const float* b2    = (const float*)d_in[12];  // [L, D]
    const float* lnf_g = (const float*)d_in[13];
    const float* lnf_b = (const float*)d_in[14];
    const float* wprj  = (const float*)d_in[15];  // [1, D]
    float* out = (float*)d_out;

    char* ws = (char*)d_ws;
    float* xcur = (float*)ws;                       ws += (size_t)NROW * D_  * 4;  // fp32 residual stream
    __hip_bfloat16* lnb = (__hip_bfloat16*)ws;      ws += (size_t)NROW * D_  * 2;  // LN output (bf16 A-operand)
    float* xg3  = (float*)ws;                       ws += (size_t)NROW * G4H * 4;  // gate proj [s][col'][16b]
    __hip_bfloat16* hb  = (__hip_bfloat16*)ws;      ws += (size_t)NROW * H_  * 2;  // LSTM h (bf16 A-operand)
    __hip_bfloat16* f1  = (__hip_bfloat16*)ws;      ws += (size_t)NROW * DI_ * 2;  // FFN hidden (bf16 A-operand)

    hipMemcpyAsync(xcur, src, (size_t)NROW * D_ * sizeof(float),
                   hipMemcpyDeviceToDevice, stream);

    for (int l = 0; l < L_; l++) {
        // --- janossy layer ---
        ln_kernel<<<NROW, 256, 0, stream>>>(xcur, ln1_g + (size_t)l * D_,
                                            ln1_b + (size_t)l * D_, lnb);
        mfma_gemm<0, 0, 0, 2><<<dim3(G4H / 64, NROW / 64), 256, 0, stream>>>(
            lnb, wih + (size_t)l * G4H * D_, nullptr, nullptr, xg3, NROW, G4H, D_);
        lstm_wave_kernel<<<dim3(S_, 2), 64, 0, stream>>>(
            xg3, whh + (size_t)l * G4H * H_, hb);
        mfma_gemm<0, 0, 1, 0><<<dim3(D_ / 64, NROW / 64), 256, 0, stream>>>(
            hb, wfc + (size_t)l * D_ * H_, nullptr, xcur, xcur, NROW, D_, H_);
        // --- FFN ---
        ln_kernel<<<NROW, 256, 0, stream>>>(xcur, ln2_g + (size_t)l * D_,
                                            ln2_b + (size_t)l * D_, lnb);
        mfma_gemm<1, 1, 0, 1><<<dim3(DI_ / 64, NROW / 64), 256, 0, stream>>>(
            lnb, w1 + (size_t)l * DI_ * D_, b1 + (size_t)l * DI_, nullptr, f1, NROW, DI_, D_);
        mfma_gemm<1, 0, 1, 0><<<dim3(D_ / 64, NROW / 64), 256, 0, stream>>>(
            f1, w2 + (size_t)l * D_ * DI_, b2 + (size_t)l * D_, xcur, xcur, NROW, D_, DI_);
    }
    final_kernel<<<NROW, 256, 0, stream>>>(xcur, lnf_g, lnf_b, wprj, out);
}

// Round 6
// 873.435 us; speedup vs baseline: 1.7197x; 1.7197x over previous
//
#include <hip/hip_runtime.h>
#include <hip/hip_bf16.h>

#define B_ 16
#define S_ 80
#define D_ 512
#define H_ 64
#define DI_ 2048
#define L_ 6
#define G4H 256            // 4*H
#define NROW (B_ * S_)     // 1280 rows = (b, s)
#define EPS_ 1e-6f

typedef __attribute__((ext_vector_type(8))) short short8;
typedef __attribute__((ext_vector_type(4))) float f32x4;

// ---------------- math helpers ----------------
__device__ __forceinline__ float sigmoidf_(float x) {
    return __fdividef(1.0f, 1.0f + __expf(-x));
}
__device__ __forceinline__ float tanh_(float x) {
    return __fdividef(2.0f, 1.0f + __expf(-2.0f * x)) - 1.0f;
}
__device__ __forceinline__ short f2bf(float f) {
    __hip_bfloat16 h = __float2bfloat16(f);   // RNE
    return *reinterpret_cast<short*>(&h);
}

// ---------------- LayerNorm: one block per row, D=512, 256 threads; bf16 out ----------------
__global__ __launch_bounds__(256)
void ln_kernel(const float* __restrict__ x, const float* __restrict__ g,
               const float* __restrict__ b, __hip_bfloat16* __restrict__ out) {
    int row = blockIdx.x;
    int t = threadIdx.x;
    const float* xr = x + (size_t)row * D_;
    float v0 = xr[t], v1 = xr[t + 256];
    __shared__ float red[256];
    red[t] = v0 + v1;
    __syncthreads();
    for (int o = 128; o > 0; o >>= 1) { if (t < o) red[t] += red[t + o]; __syncthreads(); }
    float m = red[0] * (1.0f / (float)D_);
    __syncthreads();
    float d0 = v0 - m, d1 = v1 - m;
    red[t] = d0 * d0 + d1 * d1;
    __syncthreads();
    for (int o = 128; o > 0; o >>= 1) { if (t < o) red[t] += red[t + o]; __syncthreads(); }
    float rs = rsqrtf(red[0] * (1.0f / (float)D_) + EPS_);
    __hip_bfloat16* orow = out + (size_t)row * D_;
    orow[t]       = __float2bfloat16(d0 * rs * g[t]       + b[t]);
    orow[t + 256] = __float2bfloat16(d1 * rs * g[t + 256] + b[t + 256]);
}

// ---------------- bf16 MFMA GEMM: C[M,N] = A[M,K] @ W[N,K]^T (+bias)(+relu)(+res) -----------
// OUT_MODE: 0 = fp32 row-major, 1 = bf16 row-major,
//           2 = bf16 xg4 layout [s][half][col'][slot16]:
//               col' = ((u>>4)*4 + gate)*16 + (u&15)  (orig col = gate*64 + u)
//               half = b>>3, slot = ((b&7)>>1)*4 + ((b&7)&1)   (placed C-row of batch)
template<int WITH_BIAS, int WITH_RELU, int WITH_RES, int OUT_MODE>
__global__ __launch_bounds__(256)
void mfma_gemm(const __hip_bfloat16* __restrict__ A, const float* __restrict__ W,
               const float* __restrict__ bias, const float* __restrict__ res,
               void* __restrict__ C, int M, int N, int K) {
    const int LDT = 40;  // LDS row stride in bf16 elems
    __shared__ short As[64 * LDT];
    __shared__ short Ws[64 * LDT];

    int tid  = threadIdx.x;
    int wave = tid >> 6, lane = tid & 63;
    int quad = lane >> 4, l16 = lane & 15;
    int m_off = (wave >> 1) * 32, n_off = (wave & 1) * 32;
    int m0 = blockIdx.y * 64, n0 = blockIdx.x * 64;

    int r = tid >> 2, c = tid & 3;           // staging: row 0..63, 8-elem chunk 0..3
    const short* Ag = reinterpret_cast<const short*>(A);

    f32x4 acc00 = {0.f,0.f,0.f,0.f}, acc01 = acc00, acc10 = acc00, acc11 = acc00;

    for (int k0 = 0; k0 < K; k0 += 32) {
        short8 av = *reinterpret_cast<const short8*>(&Ag[(size_t)(m0 + r) * K + k0 + c * 8]);
        const float* wrow = &W[(size_t)(n0 + r) * K + k0 + c * 8];
        float4 w0 = *reinterpret_cast<const float4*>(wrow);
        float4 w1 = *reinterpret_cast<const float4*>(wrow + 4);
        short8 wv;
        wv[0] = f2bf(w0.x); wv[1] = f2bf(w0.y); wv[2] = f2bf(w0.z); wv[3] = f2bf(w0.w);
        wv[4] = f2bf(w1.x); wv[5] = f2bf(w1.y); wv[6] = f2bf(w1.z); wv[7] = f2bf(w1.w);

        __syncthreads();
        *reinterpret_cast<short8*>(&As[r * LDT + c * 8]) = av;
        *reinterpret_cast<short8*>(&Ws[r * LDT + c * 8]) = wv;
        __syncthreads();

        short8 a0 = *reinterpret_cast<const short8*>(&As[(m_off + l16) * LDT + quad * 8]);
        short8 a1 = *reinterpret_cast<const short8*>(&As[(m_off + 16 + l16) * LDT + quad * 8]);
        short8 b0 = *reinterpret_cast<const short8*>(&Ws[(n_off + l16) * LDT + quad * 8]);
        short8 b1 = *reinterpret_cast<const short8*>(&Ws[(n_off + 16 + l16) * LDT + quad * 8]);

        acc00 = __builtin_amdgcn_mfma_f32_16x16x32_bf16(a0, b0, acc00, 0, 0, 0);
        acc01 = __builtin_amdgcn_mfma_f32_16x16x32_bf16(a0, b1, acc01, 0, 0, 0);
        acc10 = __builtin_amdgcn_mfma_f32_16x16x32_bf16(a1, b0, acc10, 0, 0, 0);
        acc11 = __builtin_amdgcn_mfma_f32_16x16x32_bf16(a1, b1, acc11, 0, 0, 0);
    }

    f32x4 accs[2][2] = {{acc00, acc01}, {acc10, acc11}};
    #pragma unroll
    for (int fi = 0; fi < 2; fi++) {
        #pragma unroll
        for (int fj = 0; fj < 2; fj++) {
            int coln = n0 + n_off + fj * 16 + l16;
            float bv = WITH_BIAS ? bias[coln] : 0.0f;
            #pragma unroll
            for (int rr = 0; rr < 4; rr++) {
                int rowm = m0 + m_off + fi * 16 + quad * 4 + rr;
                float v = accs[fi][fj][rr];
                if (WITH_BIAS) v += bv;
                if (WITH_RELU) v = fmaxf(v, 0.0f);
                if (WITH_RES)  v += res[(size_t)rowm * N + coln];
                if (OUT_MODE == 0) {
                    reinterpret_cast<float*>(C)[(size_t)rowm * N + coln] = v;
                } else if (OUT_MODE == 1) {
                    reinterpret_cast<__hip_bfloat16*>(C)[(size_t)rowm * N + coln] = __float2bfloat16(v);
                } else {
                    int b_ = rowm / S_;
                    int s_ = rowm - b_ * S_;
                    int gate = coln >> 6, u = coln & 63;
                    int cp   = ((u >> 4) * 4 + gate) * 16 + (u & 15);
                    int half = b_ >> 3, b7 = b_ & 7;
                    int slot = (b7 >> 1) * 4 + (b7 & 1);
                    reinterpret_cast<__hip_bfloat16*>(C)[
                        (((size_t)(s_ * 2 + half) * 256 + cp) << 4) + slot] = __float2bfloat16(v);
                }
            }
        }
    }
}

// ---------------- MFMA LSTM v3: xg via identity-MFMA, M=8, 1 barrier/step ----------------
// Grid (80,2): block = (output position i, batch half bh), 4 waves. Batches placed at
// C-rows {0,1,4,5,8,9,12,13} (p -> row (p>>1)*4+(p&1)) so every lane owns exactly 2
// states (r=0,1) -> transcendental issue halved, no shuffles. Wave w owns gate-tiles
// w*4+g <-> orig cols gate g*64 + w*16 + l16. Per tile per step:
//   acc = mfma(A_I, B_xg, 0); acc = mfma(h0, Whh0, acc); acc = mfma(h1, Whh1, acc)
// A_I[m][k]=delta(m,k) (constant frag) copies bf16 xg into the accumulator through the
// matrix pipe: no v_accvgpr init, and B-junk at k>=16 is auto-masked by A_I=0.
// xg fragments: ONE 16B coalesced load per tile (layout [s][bh][col'][16slots]).
// h double-buffered in LDS (parity) -> single __syncthreads per step.
__global__ __launch_bounds__(256)
void lstm_v3_kernel(const __hip_bfloat16* __restrict__ xg4,  // [S][2][256][16] bf16
                    const float* __restrict__ whh,           // [4H, H] fp32
                    __hip_bfloat16* __restrict__ hlast) {    // [B, S, H]
    const int i    = blockIdx.x;      // output position 0..79
    const int bh   = blockIdx.y;      // batch half 0..1
    const int tid  = threadIdx.x;
    const int wave = tid >> 6, lane = tid & 63;
    const int quad = lane >> 4, l16 = lane & 15;
    const int unit = wave * 16 + l16; // hidden unit owned on the C side

    // Whh B-fragments (bf16), one-time. Tile g: col n = l16 <-> whh row g*64 + unit.
    short8 bfrag[4][2];
    #pragma unroll
    for (int g = 0; g < 4; g++) {
        const float* wr = &whh[(size_t)(g * 64 + unit) * H_];
        #pragma unroll
        for (int kc = 0; kc < 2; kc++) {
            float4 x0 = *(const float4*)(wr + kc * 32 + quad * 8);
            float4 x1 = *(const float4*)(wr + kc * 32 + quad * 8 + 4);
            short8 v;
            v[0] = f2bf(x0.x); v[1] = f2bf(x0.y); v[2] = f2bf(x0.z); v[3] = f2bf(x0.w);
            v[4] = f2bf(x1.x); v[5] = f2bf(x1.y); v[6] = f2bf(x1.z); v[7] = f2bf(x1.w);
            bfrag[g][kc] = v;
        }
    }

    // constant identity A-fragment: A_I[m=l16][k=quad*8+j] = (k==l16)
    short8 aI;
    #pragma unroll
    for (int j = 0; j < 8; j++)
        aI[j] = (quad * 8 + j == l16) ? (short)0x3F80 : (short)0;

    // h in LDS, double-buffered by step parity; 72-short rows (144B, 16B-aligned)
    __shared__ __attribute__((aligned(16))) short hsh[2][16][72];
    for (int idx = tid; idx < 2 * 16 * 72; idx += 256)
        reinterpret_cast<short*>(hsh)[idx] = 0;

    float cst[2] = {0.f, 0.f};
    float hvv[2] = {0.f, 0.f};

    // per-gate xg fragment byte addresses: ((s*2+bh)*256 + (wave*4+g)*16 + l16)*16 + (quad&1)*8
    const short* xgp = reinterpret_cast<const short*>(xg4);
    size_t xbase[4];
    #pragma unroll
    for (int g = 0; g < 4; g++)
        xbase[g] = ((size_t)bh * 256 + (wave * 4 + g) * 16 + l16) * 16 + (quad & 1) * 8;

    short8 b2[4];
    {
        int s0 = (0 == i) ? (S_ - 1) : 0;
        #pragma unroll
        for (int g = 0; g < 4; g++)
            b2[g] = *reinterpret_cast<const short8*>(&xgp[(size_t)s0 * 8192 + xbase[g]]);
    }

    __syncthreads();  // LDS zero-init visible

    for (int t = 0; t < S_; t++) {
        const int pb = t & 1;
        // h_{t-1} A-fragments
        short8 af0 = *reinterpret_cast<const short8*>(&hsh[pb][l16][quad * 8]);
        short8 af1 = *reinterpret_cast<const short8*>(&hsh[pb][l16][32 + quad * 8]);

        const f32x4 z4 = {0.f, 0.f, 0.f, 0.f};
        f32x4 acc[4];
        #pragma unroll
        for (int g = 0; g < 4; g++)
            acc[g] = __builtin_amdgcn_mfma_f32_16x16x32_bf16(aI, b2[g], z4, 0, 0, 0);

        // prefetch next step's xg frags (b2 just consumed; drain covered by MFMA+trans)
        if (t + 1 < S_) {
            int tn = t + 1;
            int sn = (tn == i) ? (S_ - 1) : ((tn == S_ - 1) ? i : tn);
            #pragma unroll
            for (int g = 0; g < 4; g++)
                b2[g] = *reinterpret_cast<const short8*>(&xgp[(size_t)sn * 8192 + xbase[g]]);
        }

        #pragma unroll
        for (int g = 0; g < 4; g++) {
            acc[g] = __builtin_amdgcn_mfma_f32_16x16x32_bf16(af0, bfrag[g][0], acc[g], 0, 0, 0);
            acc[g] = __builtin_amdgcn_mfma_f32_16x16x32_bf16(af1, bfrag[g][1], acc[g], 0, 0, 0);
        }

        // nonlinearity: 2 states/lane (placed rows quad*4 + r), publish h_t to buf[t^1]
        #pragma unroll
        for (int r = 0; r < 2; r++) {
            float ig = sigmoidf_(acc[0][r]);
            float fg = sigmoidf_(acc[1][r]);
            float gg = tanh_(acc[2][r]);
            float og = sigmoidf_(acc[3][r]);
            float cc = fg * cst[r] + ig * gg;
            cst[r] = cc;
            float h = og * tanh_(cc);
            hvv[r] = h;
            hsh[pb ^ 1][quad * 4 + r][unit] = f2bf(h);
        }
        __syncthreads();
    }

    // epilogue: lane states = (batch bh*8 + quad*2 + r, unit)
    #pragma unroll
    for (int r = 0; r < 2; r++) {
        int b = bh * 8 + quad * 2 + r;
        hlast[((size_t)b * S_ + i) * H_ + unit] = __float2bfloat16(hvv[r]);
    }
}

// ---------------- final LN + projection to one logit per row ----------------
__global__ __launch_bounds__(256)
void final_kernel(const float* __restrict__ x, const float* __restrict__ g,
                  const float* __restrict__ b, const float* __restrict__ wprj,
                  float* __restrict__ out) {
    int row = blockIdx.x;
    int t = threadIdx.x;
    const float* xr = x + (size_t)row * D_;
    float v0 = xr[t], v1 = xr[t + 256];
    __shared__ float red[256];
    red[t] = v0 + v1;
    __syncthreads();
    for (int o = 128; o > 0; o >>= 1) { if (t < o) red[t] += red[t + o]; __syncthreads(); }
    float m = red[0] * (1.0f / (float)D_);
    __syncthreads();
    float d0 = v0 - m, d1 = v1 - m;
    red[t] = d0 * d0 + d1 * d1;
    __syncthreads();
    for (int o = 128; o > 0; o >>= 1) { if (t < o) red[t] += red[t + o]; __syncthreads(); }
    float rs = rsqrtf(red[0] * (1.0f / (float)D_) + EPS_);
    __syncthreads();
    float y0 = (d0 * rs * g[t] + b[t]) * wprj[t];
    float y1 = (d1 * rs * g[t + 256] + b[t + 256]) * wprj[t + 256];
    red[t] = y0 + y1;
    __syncthreads();
    for (int o = 128; o > 0; o >>= 1) { if (t < o) red[t] += red[t + o]; __syncthreads(); }
    if (t == 0) out[row] = red[0];
}

// ---------------- host ----------------
extern "C" void kernel_launch(void* const* d_in, const int* in_sizes, int n_in,
                              void* d_out, int out_size, void* d_ws, size_t ws_size,
                              hipStream_t stream) {
    const float* src   = (const float*)d_in[0];
    const float* ln1_g = (const float*)d_in[2];
    const float* ln1_b = (const float*)d_in[3];
    const float* wih   = (const float*)d_in[4];   // [L, 4H, D]
    const float* whh   = (const float*)d_in[5];   // [L, 4H, H]
    const float* wfc   = (const float*)d_in[6];   // [L, D, H]
    const float* ln2_g = (const float*)d_in[7];
    const float* ln2_b = (const float*)d_in[8];
    const float* w1    = (const float*)d_in[9];   // [L, DI, D]
    const float* b1    = (const float*)d_in[10];  // [L, DI]
    const float* w2    = (const float*)d_in[11];  // [L, D, DI]
    const float* b2    = (const float*)d_in[12];  // [L, D]
    const float* lnf_g = (const float*)d_in[13];
    const float* lnf_b = (const float*)d_in[14];
    const float* wprj  = (const float*)d_in[15];  // [1, D]
    float* out = (float*)d_out;

    char* ws = (char*)d_ws;
    float* xcur = (float*)ws;                       ws += (size_t)NROW * D_  * 4;  // fp32 residual stream
    __hip_bfloat16* lnb = (__hip_bfloat16*)ws;      ws += (size_t)NROW * D_  * 2;  // LN output (bf16 A-operand)
    __hip_bfloat16* xg4 = (__hip_bfloat16*)ws;      ws += (size_t)S_ * 2 * 256 * 16 * 2;  // gate proj bf16
    __hip_bfloat16* hb  = (__hip_bfloat16*)ws;      ws += (size_t)NROW * H_  * 2;  // LSTM h (bf16 A-operand)
    __hip_bfloat16* f1  = (__hip_bfloat16*)ws;      ws += (size_t)NROW * DI_ * 2;  // FFN hidden (bf16 A-operand)

    hipMemcpyAsync(xcur, src, (size_t)NROW * D_ * sizeof(float),
                   hipMemcpyDeviceToDevice, stream);

    for (int l = 0; l < L_; l++) {
        // --- janossy layer ---
        ln_kernel<<<NROW, 256, 0, stream>>>(xcur, ln1_g + (size_t)l * D_,
                                            ln1_b + (size_t)l * D_, lnb);
        mfma_gemm<0, 0, 0, 2><<<dim3(G4H / 64, NROW / 64), 256, 0, stream>>>(
            lnb, wih + (size_t)l * G4H * D_, nullptr, nullptr, xg4, NROW, G4H, D_);
        lstm_v3_kernel<<<dim3(S_, 2), 256, 0, stream>>>(
            xg4, whh + (size_t)l * G4H * H_, hb);
        mfma_gemm<0, 0, 1, 0><<<dim3(D_ / 64, NROW / 64), 256, 0, stream>>>(
            hb, wfc + (size_t)l * D_ * H_, nullptr, xcur, xcur, NROW, D_, H_);
        // --- FFN ---
        ln_kernel<<<NROW, 256, 0, stream>>>(xcur, ln2_g + (size_t)l * D_,
                                            ln2_b + (size_t)l * D_, lnb);
        mfma_gemm<1, 1, 0, 1><<<dim3(DI_ / 64, NROW / 64), 256, 0, stream>>>(
            lnb, w1 + (size_t)l * DI_ * D_, b1 + (size_t)l * DI_, nullptr, f1, NROW, DI_, D_);
        mfma_gemm<1, 0, 1, 0><<<dim3(D_ / 64, NROW / 64), 256, 0, stream>>>(
            f1, w2 + (size_t)l * D_ * DI_, b2 + (size_t)l * D_, xcur, xcur, NROW, D_, DI_);
    }
    final_kernel<<<NROW, 256, 0, stream>>>(xcur, lnf_g, lnf_b, wprj, out);
}

// Round 7
// 778.713 us; speedup vs baseline: 1.9289x; 1.1216x over previous
//
#include <hip/hip_runtime.h>
#include <hip/hip_bf16.h>

#define B_ 16
#define S_ 80
#define D_ 512
#define H_ 64
#define DI_ 2048
#define L_ 6
#define G4H 256            // 4*H
#define NROW (B_ * S_)     // 1280 rows = (b, s)
#define EPS_ 1e-6f

typedef __attribute__((ext_vector_type(8))) short short8;
typedef __attribute__((ext_vector_type(4))) float f32x4;

// ---------------- math helpers ----------------
__device__ __forceinline__ float sigmoidf_(float x) {
    return __fdividef(1.0f, 1.0f + __expf(-x));
}
__device__ __forceinline__ float tanh_(float x) {
    return __fdividef(2.0f, 1.0f + __expf(-2.0f * x)) - 1.0f;
}
__device__ __forceinline__ short f2bf(float f) {
    __hip_bfloat16 h = __float2bfloat16(f);   // RNE
    return *reinterpret_cast<short*>(&h);
}

// ---------------- LayerNorm: one block per row, D=512, 256 threads; bf16 out ----------------
__global__ __launch_bounds__(256)
void ln_kernel(const float* __restrict__ x, const float* __restrict__ g,
               const float* __restrict__ b, __hip_bfloat16* __restrict__ out) {
    int row = blockIdx.x;
    int t = threadIdx.x;
    const float* xr = x + (size_t)row * D_;
    float v0 = xr[t], v1 = xr[t + 256];
    __shared__ float red[256];
    red[t] = v0 + v1;
    __syncthreads();
    for (int o = 128; o > 0; o >>= 1) { if (t < o) red[t] += red[t + o]; __syncthreads(); }
    float m = red[0] * (1.0f / (float)D_);
    __syncthreads();
    float d0 = v0 - m, d1 = v1 - m;
    red[t] = d0 * d0 + d1 * d1;
    __syncthreads();
    for (int o = 128; o > 0; o >>= 1) { if (t < o) red[t] += red[t + o]; __syncthreads(); }
    float rs = rsqrtf(red[0] * (1.0f / (float)D_) + EPS_);
    __hip_bfloat16* orow = out + (size_t)row * D_;
    orow[t]       = __float2bfloat16(d0 * rs * g[t]       + b[t]);
    orow[t + 256] = __float2bfloat16(d1 * rs * g[t + 256] + b[t + 256]);
}

// ---------------- bf16 MFMA GEMM: C[M,N] = A[M,K] @ W[N,K]^T (+bias)(+relu)(+res) -----------
// BK=64, register-prefetch pipeline: next tile's global loads are issued AFTER the
// second barrier, so their vmcnt(0) drain (at the next iteration's first barrier) is
// covered by a full compute phase (8 ds_read_b128 + 8 MFMA) instead of being serial.
// OUT_MODE: 0 = fp32 row-major, 1 = bf16 row-major,
//           2 = bf16 xg4 layout [s][half][col'][slot16]:
//               col' = ((u>>4)*4 + gate)*16 + (u&15)  (orig col = gate*64 + u)
//               half = b>>3, slot = ((b&7)>>1)*4 + ((b&7)&1)   (placed C-row of batch)
template<int WITH_BIAS, int WITH_RELU, int WITH_RES, int OUT_MODE>
__global__ __launch_bounds__(256)
void mfma_gemm(const __hip_bfloat16* __restrict__ A, const float* __restrict__ W,
               const float* __restrict__ bias, const float* __restrict__ res,
               void* __restrict__ C, int M, int N, int K) {
    const int LDT = 72;  // LDS row stride in shorts (144B rows, 16B-aligned)
    __shared__ short As[64 * LDT];
    __shared__ short Ws[64 * LDT];

    int tid  = threadIdx.x;
    int wave = tid >> 6, lane = tid & 63;
    int quad = lane >> 4, l16 = lane & 15;
    int m_off = (wave >> 1) * 32, n_off = (wave & 1) * 32;
    int m0 = blockIdx.y * 64, n0 = blockIdx.x * 64;

    int r = tid >> 2, c = tid & 3;           // staging: row 0..63, 16-elem chunk 0..3
    const short* Ag = reinterpret_cast<const short*>(A);

    f32x4 acc00 = {0.f,0.f,0.f,0.f}, acc01 = acc00, acc10 = acc00, acc11 = acc00;

    short8 avA[2], avW[2];                   // staged tile in registers
    auto load_tile = [&](int k0) {
        const short* arow = &Ag[(size_t)(m0 + r) * K + k0 + c * 16];
        avA[0] = *reinterpret_cast<const short8*>(arow);
        avA[1] = *reinterpret_cast<const short8*>(arow + 8);
        const float* wrow = &W[(size_t)(n0 + r) * K + k0 + c * 16];
        #pragma unroll
        for (int h = 0; h < 2; h++) {
            float4 x0 = *reinterpret_cast<const float4*>(wrow + h * 8);
            float4 x1 = *reinterpret_cast<const float4*>(wrow + h * 8 + 4);
            short8 v;
            v[0] = f2bf(x0.x); v[1] = f2bf(x0.y); v[2] = f2bf(x0.z); v[3] = f2bf(x0.w);
            v[4] = f2bf(x1.x); v[5] = f2bf(x1.y); v[6] = f2bf(x1.z); v[7] = f2bf(x1.w);
            avW[h] = v;
        }
    };

    load_tile(0);                            // prologue
    for (int k0 = 0; k0 < K; k0 += 64) {
        __syncthreads();                     // prev frag reads done (also drains prefetch vmem)
        *reinterpret_cast<short8*>(&As[r * LDT + c * 16])     = avA[0];
        *reinterpret_cast<short8*>(&As[r * LDT + c * 16 + 8]) = avA[1];
        *reinterpret_cast<short8*>(&Ws[r * LDT + c * 16])     = avW[0];
        *reinterpret_cast<short8*>(&Ws[r * LDT + c * 16 + 8]) = avW[1];
        __syncthreads();
        if (k0 + 64 < K) load_tile(k0 + 64); // issue next loads; drain covered by compute

        #pragma unroll
        for (int kc = 0; kc < 2; kc++) {
            short8 a0 = *reinterpret_cast<const short8*>(&As[(m_off + l16) * LDT + kc * 32 + quad * 8]);
            short8 a1 = *reinterpret_cast<const short8*>(&As[(m_off + 16 + l16) * LDT + kc * 32 + quad * 8]);
            short8 b0 = *reinterpret_cast<const short8*>(&Ws[(n_off + l16) * LDT + kc * 32 + quad * 8]);
            short8 b1 = *reinterpret_cast<const short8*>(&Ws[(n_off + 16 + l16) * LDT + kc * 32 + quad * 8]);
            acc00 = __builtin_amdgcn_mfma_f32_16x16x32_bf16(a0, b0, acc00, 0, 0, 0);
            acc01 = __builtin_amdgcn_mfma_f32_16x16x32_bf16(a0, b1, acc01, 0, 0, 0);
            acc10 = __builtin_amdgcn_mfma_f32_16x16x32_bf16(a1, b0, acc10, 0, 0, 0);
            acc11 = __builtin_amdgcn_mfma_f32_16x16x32_bf16(a1, b1, acc11, 0, 0, 0);
        }
    }

    f32x4 accs[2][2] = {{acc00, acc01}, {acc10, acc11}};
    #pragma unroll
    for (int fi = 0; fi < 2; fi++) {
        #pragma unroll
        for (int fj = 0; fj < 2; fj++) {
            int coln = n0 + n_off + fj * 16 + l16;
            float bv = WITH_BIAS ? bias[coln] : 0.0f;
            #pragma unroll
            for (int rr = 0; rr < 4; rr++) {
                int rowm = m0 + m_off + fi * 16 + quad * 4 + rr;
                float v = accs[fi][fj][rr];
                if (WITH_BIAS) v += bv;
                if (WITH_RELU) v = fmaxf(v, 0.0f);
                if (WITH_RES)  v += res[(size_t)rowm * N + coln];
                if (OUT_MODE == 0) {
                    reinterpret_cast<float*>(C)[(size_t)rowm * N + coln] = v;
                } else if (OUT_MODE == 1) {
                    reinterpret_cast<__hip_bfloat16*>(C)[(size_t)rowm * N + coln] = __float2bfloat16(v);
                } else {
                    int b_ = rowm / S_;
                    int s_ = rowm - b_ * S_;
                    int gate = coln >> 6, u = coln & 63;
                    int cp   = ((u >> 4) * 4 + gate) * 16 + (u & 15);
                    int half = b_ >> 3, b7 = b_ & 7;
                    int slot = (b7 >> 1) * 4 + (b7 & 1);
                    reinterpret_cast<__hip_bfloat16*>(C)[
                        (((size_t)(s_ * 2 + half) * 256 + cp) << 4) + slot] = __float2bfloat16(v);
                }
            }
        }
    }
}

// ---------------- MFMA LSTM v3: xg via identity-MFMA, M=8, 1 barrier/step ----------------
__global__ __launch_bounds__(256)
void lstm_v3_kernel(const __hip_bfloat16* __restrict__ xg4,  // [S][2][256][16] bf16
                    const float* __restrict__ whh,           // [4H, H] fp32
                    __hip_bfloat16* __restrict__ hlast) {    // [B, S, H]
    const int i    = blockIdx.x;      // output position 0..79
    const int bh   = blockIdx.y;      // batch half 0..1
    const int tid  = threadIdx.x;
    const int wave = tid >> 6, lane = tid & 63;
    const int quad = lane >> 4, l16 = lane & 15;
    const int unit = wave * 16 + l16; // hidden unit owned on the C side

    // Whh B-fragments (bf16), one-time. Tile g: col n = l16 <-> whh row g*64 + unit.
    short8 bfrag[4][2];
    #pragma unroll
    for (int g = 0; g < 4; g++) {
        const float* wr = &whh[(size_t)(g * 64 + unit) * H_];
        #pragma unroll
        for (int kc = 0; kc < 2; kc++) {
            float4 x0 = *(const float4*)(wr + kc * 32 + quad * 8);
            float4 x1 = *(const float4*)(wr + kc * 32 + quad * 8 + 4);
            short8 v;
            v[0] = f2bf(x0.x); v[1] = f2bf(x0.y); v[2] = f2bf(x0.z); v[3] = f2bf(x0.w);
            v[4] = f2bf(x1.x); v[5] = f2bf(x1.y); v[6] = f2bf(x1.z); v[7] = f2bf(x1.w);
            bfrag[g][kc] = v;
        }
    }

    // constant identity A-fragment: A_I[m=l16][k=quad*8+j] = (k==l16)
    short8 aI;
    #pragma unroll
    for (int j = 0; j < 8; j++)
        aI[j] = (quad * 8 + j == l16) ? (short)0x3F80 : (short)0;

    // h in LDS, double-buffered by step parity; 72-short rows (144B, 16B-aligned)
    __shared__ __attribute__((aligned(16))) short hsh[2][16][72];
    for (int idx = tid; idx < 2 * 16 * 72; idx += 256)
        reinterpret_cast<short*>(hsh)[idx] = 0;

    float cst[2] = {0.f, 0.f};
    float hvv[2] = {0.f, 0.f};

    // per-gate xg fragment byte addresses
    const short* xgp = reinterpret_cast<const short*>(xg4);
    size_t xbase[4];
    #pragma unroll
    for (int g = 0; g < 4; g++)
        xbase[g] = ((size_t)bh * 256 + (wave * 4 + g) * 16 + l16) * 16 + (quad & 1) * 8;

    short8 b2[4];
    {
        int s0 = (0 == i) ? (S_ - 1) : 0;
        #pragma unroll
        for (int g = 0; g < 4; g++)
            b2[g] = *reinterpret_cast<const short8*>(&xgp[(size_t)s0 * 8192 + xbase[g]]);
    }

    __syncthreads();  // LDS zero-init visible

    for (int t = 0; t < S_; t++) {
        const int pb = t & 1;
        short8 af0 = *reinterpret_cast<const short8*>(&hsh[pb][l16][quad * 8]);
        short8 af1 = *reinterpret_cast<const short8*>(&hsh[pb][l16][32 + quad * 8]);

        const f32x4 z4 = {0.f, 0.f, 0.f, 0.f};
        f32x4 acc[4];
        #pragma unroll
        for (int g = 0; g < 4; g++)
            acc[g] = __builtin_amdgcn_mfma_f32_16x16x32_bf16(aI, b2[g], z4, 0, 0, 0);

        if (t + 1 < S_) {
            int tn = t + 1;
            int sn = (tn == i) ? (S_ - 1) : ((tn == S_ - 1) ? i : tn);
            #pragma unroll
            for (int g = 0; g < 4; g++)
                b2[g] = *reinterpret_cast<const short8*>(&xgp[(size_t)sn * 8192 + xbase[g]]);
        }

        #pragma unroll
        for (int g = 0; g < 4; g++) {
            acc[g] = __builtin_amdgcn_mfma_f32_16x16x32_bf16(af0, bfrag[g][0], acc[g], 0, 0, 0);
            acc[g] = __builtin_amdgcn_mfma_f32_16x16x32_bf16(af1, bfrag[g][1], acc[g], 0, 0, 0);
        }

        #pragma unroll
        for (int r = 0; r < 2; r++) {
            float ig = sigmoidf_(acc[0][r]);
            float fg = sigmoidf_(acc[1][r]);
            float gg = tanh_(acc[2][r]);
            float og = sigmoidf_(acc[3][r]);
            float cc = fg * cst[r] + ig * gg;
            cst[r] = cc;
            float h = og * tanh_(cc);
            hvv[r] = h;
            hsh[pb ^ 1][quad * 4 + r][unit] = f2bf(h);
        }
        __syncthreads();
    }

    #pragma unroll
    for (int r = 0; r < 2; r++) {
        int b = bh * 8 + quad * 2 + r;
        hlast[((size_t)b * S_ + i) * H_ + unit] = __float2bfloat16(hvv[r]);
    }
}

// ---------------- final LN + projection to one logit per row ----------------
__global__ __launch_bounds__(256)
void final_kernel(const float* __restrict__ x, const float* __restrict__ g,
                  const float* __restrict__ b, const float* __restrict__ wprj,
                  float* __restrict__ out) {
    int row = blockIdx.x;
    int t = threadIdx.x;
    const float* xr = x + (size_t)row * D_;
    float v0 = xr[t], v1 = xr[t + 256];
    __shared__ float red[256];
    red[t] = v0 + v1;
    __syncthreads();
    for (int o = 128; o > 0; o >>= 1) { if (t < o) red[t] += red[t + o]; __syncthreads(); }
    float m = red[0] * (1.0f / (float)D_);
    __syncthreads();
    float d0 = v0 - m, d1 = v1 - m;
    red[t] = d0 * d0 + d1 * d1;
    __syncthreads();
    for (int o = 128; o > 0; o >>= 1) { if (t < o) red[t] += red[t + o]; __syncthreads(); }
    float rs = rsqrtf(red[0] * (1.0f / (float)D_) + EPS_);
    __syncthreads();
    float y0 = (d0 * rs * g[t] + b[t]) * wprj[t];
    float y1 = (d1 * rs * g[t + 256] + b[t + 256]) * wprj[t + 256];
    red[t] = y0 + y1;
    __syncthreads();
    for (int o = 128; o > 0; o >>= 1) { if (t < o) red[t] += red[t + o]; __syncthreads(); }
    if (t == 0) out[row] = red[0];
}

// ---------------- host ----------------
extern "C" void kernel_launch(void* const* d_in, const int* in_sizes, int n_in,
                              void* d_out, int out_size, void* d_ws, size_t ws_size,
                              hipStream_t stream) {
    const float* src   = (const float*)d_in[0];
    const float* ln1_g = (const float*)d_in[2];
    const float* ln1_b = (const float*)d_in[3];
    const float* wih   = (const float*)d_in[4];   // [L, 4H, D]
    const float* whh   = (const float*)d_in[5];   // [L, 4H, H]
    const float* wfc   = (const float*)d_in[6];   // [L, D, H]
    const float* ln2_g = (const float*)d_in[7];
    const float* ln2_b = (const float*)d_in[8];
    const float* w1    = (const float*)d_in[9];   // [L, DI, D]
    const float* b1    = (const float*)d_in[10];  // [L, DI]
    const float* w2    = (const float*)d_in[11];  // [L, D, DI]
    const float* b2    = (const float*)d_in[12];  // [L, D]
    const float* lnf_g = (const float*)d_in[13];
    const float* lnf_b = (const float*)d_in[14];
    const float* wprj  = (const float*)d_in[15];  // [1, D]
    float* out = (float*)d_out;

    char* ws = (char*)d_ws;
    float* xcur = (float*)ws;                       ws += (size_t)NROW * D_  * 4;  // fp32 residual stream
    __hip_bfloat16* lnb = (__hip_bfloat16*)ws;      ws += (size_t)NROW * D_  * 2;  // LN output (bf16 A-operand)
    __hip_bfloat16* xg4 = (__hip_bfloat16*)ws;      ws += (size_t)S_ * 2 * 256 * 16 * 2;  // gate proj bf16
    __hip_bfloat16* hb  = (__hip_bfloat16*)ws;      ws += (size_t)NROW * H_  * 2;  // LSTM h (bf16 A-operand)
    __hip_bfloat16* f1  = (__hip_bfloat16*)ws;      ws += (size_t)NROW * DI_ * 2;  // FFN hidden (bf16 A-operand)

    hipMemcpyAsync(xcur, src, (size_t)NROW * D_ * sizeof(float),
                   hipMemcpyDeviceToDevice, stream);

    for (int l = 0; l < L_; l++) {
        // --- janossy layer ---
        ln_kernel<<<NROW, 256, 0, stream>>>(xcur, ln1_g + (size_t)l * D_,
                                            ln1_b + (size_t)l * D_, lnb);
        mfma_gemm<0, 0, 0, 2><<<dim3(G4H / 64, NROW / 64), 256, 0, stream>>>(
            lnb, wih + (size_t)l * G4H * D_, nullptr, nullptr, xg4, NROW, G4H, D_);
        lstm_v3_kernel<<<dim3(S_, 2), 256, 0, stream>>>(
            xg4, whh + (size_t)l * G4H * H_, hb);
        mfma_gemm<0, 0, 1, 0><<<dim3(D_ / 64, NROW / 64), 256, 0, stream>>>(
            hb, wfc + (size_t)l * D_ * H_, nullptr, xcur, xcur, NROW, D_, H_);
        // --- FFN ---
        ln_kernel<<<NROW, 256, 0, stream>>>(xcur, ln2_g + (size_t)l * D_,
                                            ln2_b + (size_t)l * D_, lnb);
        mfma_gemm<1, 1, 0, 1><<<dim3(DI_ / 64, NROW / 64), 256, 0, stream>>>(
            lnb, w1 + (size_t)l * DI_ * D_, b1 + (size_t)l * DI_, nullptr, f1, NROW, DI_, D_);
        mfma_gemm<1, 0, 1, 0><<<dim3(D_ / 64, NROW / 64), 256, 0, stream>>>(
            f1, w2 + (size_t)l * D_ * DI_, b2 + (size_t)l * D_, xcur, xcur, NROW, D_, DI_);
    }
    final_kernel<<<NROW, 256, 0, stream>>>(xcur, lnf_g, lnf_b, wprj, out);
}

// Round 8
// 716.375 us; speedup vs baseline: 2.0967x; 1.0870x over previous
//
#include <hip/hip_runtime.h>
#include <hip/hip_bf16.h>

#define B_ 16
#define S_ 80
#define D_ 512
#define H_ 64
#define DI_ 2048
#define L_ 6
#define G4H 256            // 4*H
#define NROW (B_ * S_)     // 1280 rows = (b, s)
#define EPS_ 1e-6f

typedef __attribute__((ext_vector_type(8))) short short8;
typedef __attribute__((ext_vector_type(4))) float f32x4;

// ---------------- math helpers ----------------
__device__ __forceinline__ float sigmoidf_(float x) {
    return __fdividef(1.0f, 1.0f + __expf(-x));
}
__device__ __forceinline__ float tanh_(float x) {
    return __fdividef(2.0f, 1.0f + __expf(-2.0f * x)) - 1.0f;
}
__device__ __forceinline__ short f2bf(float f) {
    __hip_bfloat16 h = __float2bfloat16(f);   // RNE
    return *reinterpret_cast<short*>(&h);
}

// ---------------- fp32 -> bf16 weight conversion (once per launch) ----------------
__global__ __launch_bounds__(256)
void w2bf_kernel(const float* __restrict__ s, __hip_bfloat16* __restrict__ d, int n4) {
    int i = blockIdx.x * 256 + threadIdx.x;
    if (i < n4) {
        float4 v = reinterpret_cast<const float4*>(s)[i];
        short4 o;
        o.x = f2bf(v.x); o.y = f2bf(v.y); o.z = f2bf(v.z); o.w = f2bf(v.w);
        reinterpret_cast<short4*>(d)[i] = o;
    }
}

// ---------------- LayerNorm: one block per row, shuffle reduce (2 barriers) ----------------
__global__ __launch_bounds__(256)
void ln_kernel(const float* __restrict__ x, const float* __restrict__ g,
               const float* __restrict__ b, __hip_bfloat16* __restrict__ out) {
    int row = blockIdx.x;
    int t = threadIdx.x;
    const float* xr = x + (size_t)row * D_;
    float v0 = xr[t], v1 = xr[t + 256];
    __shared__ float ws4[4], qs4[4];
    float s = v0 + v1;
    #pragma unroll
    for (int o = 32; o > 0; o >>= 1) s += __shfl_down(s, o);
    if ((t & 63) == 0) ws4[t >> 6] = s;
    __syncthreads();
    float m = (ws4[0] + ws4[1] + ws4[2] + ws4[3]) * (1.0f / (float)D_);
    float d0 = v0 - m, d1 = v1 - m;
    float q = d0 * d0 + d1 * d1;
    #pragma unroll
    for (int o = 32; o > 0; o >>= 1) q += __shfl_down(q, o);
    if ((t & 63) == 0) qs4[t >> 6] = q;
    __syncthreads();
    float rs = rsqrtf((qs4[0] + qs4[1] + qs4[2] + qs4[3]) * (1.0f / (float)D_) + EPS_);
    __hip_bfloat16* orow = out + (size_t)row * D_;
    orow[t]       = __float2bfloat16(d0 * rs * g[t]       + b[t]);
    orow[t + 256] = __float2bfloat16(d1 * rs * g[t + 256] + b[t + 256]);
}

// ---------------- bf16 MFMA GEMM: C[M,N] = A[M,K] @ W[N,K]^T (+bias)(+relu)(+res) -----------
// A and W both bf16 row-major (weights pre-converted). BK=64, register-prefetch
// pipeline: next tile's loads issue AFTER the second barrier so their vmcnt drain
// (next iteration's first barrier) is covered by the compute phase.
// OUT_MODE: 0 = fp32 row-major, 1 = bf16 row-major,
//           2 = fp32 xg5 layout [s][half][gate][unit64][slot8]  (half=b>>3, slot=b&7)
template<int WITH_BIAS, int WITH_RELU, int WITH_RES, int OUT_MODE>
__global__ __launch_bounds__(256)
void mfma_gemm(const __hip_bfloat16* __restrict__ A, const __hip_bfloat16* __restrict__ W,
               const float* __restrict__ bias, const float* __restrict__ res,
               void* __restrict__ C, int M, int N, int K) {
    const int LDT = 72;  // LDS row stride in shorts (144B rows, 16B-aligned)
    __shared__ short As[64 * LDT];
    __shared__ short Ws[64 * LDT];

    int tid  = threadIdx.x;
    int wave = tid >> 6, lane = tid & 63;
    int quad = lane >> 4, l16 = lane & 15;
    int m_off = (wave >> 1) * 32, n_off = (wave & 1) * 32;
    int m0 = blockIdx.y * 64, n0 = blockIdx.x * 64;

    int r = tid >> 2, c = tid & 3;           // staging: row 0..63, 16-elem chunk 0..3
    const short* Ag = reinterpret_cast<const short*>(A);
    const short* Wg = reinterpret_cast<const short*>(W);

    f32x4 acc00 = {0.f,0.f,0.f,0.f}, acc01 = acc00, acc10 = acc00, acc11 = acc00;

    short8 avA[2], avW[2];                   // staged tile in registers
    auto load_tile = [&](int k0) {
        const short* arow = &Ag[(size_t)(m0 + r) * K + k0 + c * 16];
        avA[0] = *reinterpret_cast<const short8*>(arow);
        avA[1] = *reinterpret_cast<const short8*>(arow + 8);
        const short* wrow = &Wg[(size_t)(n0 + r) * K + k0 + c * 16];
        avW[0] = *reinterpret_cast<const short8*>(wrow);
        avW[1] = *reinterpret_cast<const short8*>(wrow + 8);
    };

    load_tile(0);                            // prologue
    for (int k0 = 0; k0 < K; k0 += 64) {
        __syncthreads();                     // prev frag reads done (also drains prefetch vmem)
        *reinterpret_cast<short8*>(&As[r * LDT + c * 16])     = avA[0];
        *reinterpret_cast<short8*>(&As[r * LDT + c * 16 + 8]) = avA[1];
        *reinterpret_cast<short8*>(&Ws[r * LDT + c * 16])     = avW[0];
        *reinterpret_cast<short8*>(&Ws[r * LDT + c * 16 + 8]) = avW[1];
        __syncthreads();
        if (k0 + 64 < K) load_tile(k0 + 64); // issue next loads; drain covered by compute

        #pragma unroll
        for (int kc = 0; kc < 2; kc++) {
            short8 a0 = *reinterpret_cast<const short8*>(&As[(m_off + l16) * LDT + kc * 32 + quad * 8]);
            short8 a1 = *reinterpret_cast<const short8*>(&As[(m_off + 16 + l16) * LDT + kc * 32 + quad * 8]);
            short8 b0 = *reinterpret_cast<const short8*>(&Ws[(n_off + l16) * LDT + kc * 32 + quad * 8]);
            short8 b1 = *reinterpret_cast<const short8*>(&Ws[(n_off + 16 + l16) * LDT + kc * 32 + quad * 8]);
            acc00 = __builtin_amdgcn_mfma_f32_16x16x32_bf16(a0, b0, acc00, 0, 0, 0);
            acc01 = __builtin_amdgcn_mfma_f32_16x16x32_bf16(a0, b1, acc01, 0, 0, 0);
            acc10 = __builtin_amdgcn_mfma_f32_16x16x32_bf16(a1, b0, acc10, 0, 0, 0);
            acc11 = __builtin_amdgcn_mfma_f32_16x16x32_bf16(a1, b1, acc11, 0, 0, 0);
        }
    }

    f32x4 accs[2][2] = {{acc00, acc01}, {acc10, acc11}};
    #pragma unroll
    for (int fi = 0; fi < 2; fi++) {
        #pragma unroll
        for (int fj = 0; fj < 2; fj++) {
            int coln = n0 + n_off + fj * 16 + l16;
            float bv = WITH_BIAS ? bias[coln] : 0.0f;
            #pragma unroll
            for (int rr = 0; rr < 4; rr++) {
                int rowm = m0 + m_off + fi * 16 + quad * 4 + rr;
                float v = accs[fi][fj][rr];
                if (WITH_BIAS) v += bv;
                if (WITH_RELU) v = fmaxf(v, 0.0f);
                if (WITH_RES)  v += res[(size_t)rowm * N + coln];
                if (OUT_MODE == 0) {
                    reinterpret_cast<float*>(C)[(size_t)rowm * N + coln] = v;
                } else if (OUT_MODE == 1) {
                    reinterpret_cast<__hip_bfloat16*>(C)[(size_t)rowm * N + coln] = __float2bfloat16(v);
                } else {
                    int b_ = rowm / S_;
                    int s_ = rowm - b_ * S_;
                    int gate = coln >> 6, u = coln & 63;
                    int half = b_ >> 3, slot = b_ & 7;
                    reinterpret_cast<float*>(C)[
                        ((((size_t)(s_ * 2 + half) * 4 + gate) * 64 + u) << 3) + slot] = v;
                }
            }
        }
    }
}

// ---------------- MFMA LSTM v4: fp32 C-init from xg, M=8, 1 barrier/step ----------------
// Grid (80,2): block = (output position i, batch half bh), 4 waves. Batches placed at
// C-rows {0,1,4,5,...} (b7=quad*2+r) so every lane owns exactly 2 states. Wave w owns
// gate-tiles for units w*16+l16. Per gate per step the chain is only 2 MFMAs deep:
//   acc = {xg0, xg1, xg0, xg1};  acc = mfma(h0, Whh0, acc);  acc = mfma(h1, Whh1, acc)
// xg arrives as ONE coalesced float2 per gate from layout [s][half][gate][unit][slot8].
// h double-buffered in LDS (parity) -> single __syncthreads per step.
__global__ __launch_bounds__(256)
void lstm_v4_kernel(const float* __restrict__ xg5,  // [S][2][4][64][8] fp32
                    const float* __restrict__ whh,  // [4H, H] fp32
                    __hip_bfloat16* __restrict__ hlast) {  // [B, S, H]
    const int i    = blockIdx.x;      // output position 0..79
    const int bh   = blockIdx.y;      // batch half 0..1
    const int tid  = threadIdx.x;
    const int wave = tid >> 6, lane = tid & 63;
    const int quad = lane >> 4, l16 = lane & 15;
    const int unit = wave * 16 + l16; // hidden unit owned on the C side

    // Whh B-fragments (bf16), one-time. Tile g: col n = l16 <-> whh row g*64 + unit.
    short8 bfrag[4][2];
    #pragma unroll
    for (int g = 0; g < 4; g++) {
        const float* wr = &whh[(size_t)(g * 64 + unit) * H_];
        #pragma unroll
        for (int kc = 0; kc < 2; kc++) {
            float4 x0 = *(const float4*)(wr + kc * 32 + quad * 8);
            float4 x1 = *(const float4*)(wr + kc * 32 + quad * 8 + 4);
            short8 v;
            v[0] = f2bf(x0.x); v[1] = f2bf(x0.y); v[2] = f2bf(x0.z); v[3] = f2bf(x0.w);
            v[4] = f2bf(x1.x); v[5] = f2bf(x1.y); v[6] = f2bf(x1.z); v[7] = f2bf(x1.w);
            bfrag[g][kc] = v;
        }
    }

    // h in LDS, double-buffered by step parity; 72-short rows (144B, 16B-aligned)
    __shared__ __attribute__((aligned(16))) short hsh[2][16][72];
    for (int idx = tid; idx < 2 * 16 * 72; idx += 256)
        reinterpret_cast<short*>(hsh)[idx] = 0;

    float cst[2] = {0.f, 0.f};
    float hvv[2] = {0.f, 0.f};

    // xg float2 addresses: (((s*2+bh)*4 + g)*64 + unit)*8 + quad*2
    size_t xoff[4];
    #pragma unroll
    for (int g = 0; g < 4; g++)
        xoff[g] = ((((size_t)bh * 4 + g) * 64 + unit) << 3) + quad * 2;

    float2 xv[4];
    {
        int s0 = (0 == i) ? (S_ - 1) : 0;
        #pragma unroll
        for (int g = 0; g < 4; g++)
            xv[g] = *reinterpret_cast<const float2*>(&xg5[(size_t)s0 * 4096 + xoff[g]]);
    }

    __syncthreads();  // LDS zero-init visible

    for (int t = 0; t < S_; t++) {
        const int pb = t & 1;
        short8 af0 = *reinterpret_cast<const short8*>(&hsh[pb][l16][quad * 8]);
        short8 af1 = *reinterpret_cast<const short8*>(&hsh[pb][l16][32 + quad * 8]);

        f32x4 acc[4];
        #pragma unroll
        for (int g = 0; g < 4; g++) {
            f32x4 a = {xv[g].x, xv[g].y, xv[g].x, xv[g].y};  // rows 2,3 unused
            acc[g] = a;
        }

        // prefetch next step's xg (xv just consumed; drain covered by MFMA+nonlin)
        if (t + 1 < S_) {
            int tn = t + 1;
            int sn = (tn == i) ? (S_ - 1) : ((tn == S_ - 1) ? i : tn);
            #pragma unroll
            for (int g = 0; g < 4; g++)
                xv[g] = *reinterpret_cast<const float2*>(&xg5[(size_t)sn * 4096 + xoff[g]]);
        }

        #pragma unroll
        for (int g = 0; g < 4; g++) {
            acc[g] = __builtin_amdgcn_mfma_f32_16x16x32_bf16(af0, bfrag[g][0], acc[g], 0, 0, 0);
            acc[g] = __builtin_amdgcn_mfma_f32_16x16x32_bf16(af1, bfrag[g][1], acc[g], 0, 0, 0);
        }

        #pragma unroll
        for (int r = 0; r < 2; r++) {
            float ig = sigmoidf_(acc[0][r]);
            float fg = sigmoidf_(acc[1][r]);
            float gg = tanh_(acc[2][r]);
            float og = sigmoidf_(acc[3][r]);
            float cc = fg * cst[r] + ig * gg;
            cst[r] = cc;
            float h = og * tanh_(cc);
            hvv[r] = h;
            hsh[pb ^ 1][quad * 4 + r][unit] = f2bf(h);
        }
        __syncthreads();
    }

    #pragma unroll
    for (int r = 0; r < 2; r++) {
        int b = bh * 8 + quad * 2 + r;
        hlast[((size_t)b * S_ + i) * H_ + unit] = __float2bfloat16(hvv[r]);
    }
}

// ---------------- final LN + projection to one logit per row ----------------
__global__ __launch_bounds__(256)
void final_kernel(const float* __restrict__ x, const float* __restrict__ g,
                  const float* __restrict__ b, const float* __restrict__ wprj,
                  float* __restrict__ out) {
    int row = blockIdx.x;
    int t = threadIdx.x;
    const float* xr = x + (size_t)row * D_;
    float v0 = xr[t], v1 = xr[t + 256];
    __shared__ float red[256];
    red[t] = v0 + v1;
    __syncthreads();
    for (int o = 128; o > 0; o >>= 1) { if (t < o) red[t] += red[t + o]; __syncthreads(); }
    float m = red[0] * (1.0f / (float)D_);
    __syncthreads();
    float d0 = v0 - m, d1 = v1 - m;
    red[t] = d0 * d0 + d1 * d1;
    __syncthreads();
    for (int o = 128; o > 0; o >>= 1) { if (t < o) red[t] += red[t + o]; __syncthreads(); }
    float rs = rsqrtf(red[0] * (1.0f / (float)D_) + EPS_);
    __syncthreads();
    float y0 = (d0 * rs * g[t] + b[t]) * wprj[t];
    float y1 = (d1 * rs * g[t + 256] + b[t + 256]) * wprj[t + 256];
    red[t] = y0 + y1;
    __syncthreads();
    for (int o = 128; o > 0; o >>= 1) { if (t < o) red[t] += red[t + o]; __syncthreads(); }
    if (t == 0) out[row] = red[0];
}

// ---------------- host ----------------
extern "C" void kernel_launch(void* const* d_in, const int* in_sizes, int n_in,
                              void* d_out, int out_size, void* d_ws, size_t ws_size,
                              hipStream_t stream) {
    const float* src   = (const float*)d_in[0];
    const float* ln1_g = (const float*)d_in[2];
    const float* ln1_b = (const float*)d_in[3];
    const float* wih   = (const float*)d_in[4];   // [L, 4H, D]
    const float* whh   = (const float*)d_in[5];   // [L, 4H, H]
    const float* wfc   = (const float*)d_in[6];   // [L, D, H]
    const float* ln2_g = (const float*)d_in[7];
    const float* ln2_b = (const float*)d_in[8];
    const float* w1    = (const float*)d_in[9];   // [L, DI, D]
    const float* b1    = (const float*)d_in[10];  // [L, DI]
    const float* w2    = (const float*)d_in[11];  // [L, D, DI]
    const float* b2    = (const float*)d_in[12];  // [L, D]
    const float* lnf_g = (const float*)d_in[13];
    const float* lnf_b = (const float*)d_in[14];
    const float* wprj  = (const float*)d_in[15];  // [1, D]
    float* out = (float*)d_out;

    char* ws = (char*)d_ws;
    float* xcur = (float*)ws;                       ws += (size_t)NROW * D_  * 4;  // fp32 residual stream
    __hip_bfloat16* lnb = (__hip_bfloat16*)ws;      ws += (size_t)NROW * D_  * 2;  // LN output (bf16 A-operand)
    float* xg5  = (float*)ws;                       ws += (size_t)S_ * 4096  * 4;  // gate proj fp32 [s][2][4][64][8]
    __hip_bfloat16* hb  = (__hip_bfloat16*)ws;      ws += (size_t)NROW * H_  * 2;  // LSTM h (bf16 A-operand)
    __hip_bfloat16* f1  = (__hip_bfloat16*)ws;      ws += (size_t)NROW * DI_ * 2;  // FFN hidden (bf16 A-operand)
    __hip_bfloat16* wihb = (__hip_bfloat16*)ws;     ws += (size_t)L_ * G4H * D_ * 2;
    __hip_bfloat16* wfcb = (__hip_bfloat16*)ws;     ws += (size_t)L_ * D_ * H_ * 2;
    __hip_bfloat16* w1b  = (__hip_bfloat16*)ws;     ws += (size_t)L_ * DI_ * D_ * 2;
    __hip_bfloat16* w2b  = (__hip_bfloat16*)ws;     ws += (size_t)L_ * D_ * DI_ * 2;

    // one-time (per launch) weight conversions to bf16
    {
        int n4;
        n4 = L_ * G4H * D_ / 4;
        w2bf_kernel<<<(n4 + 255) / 256, 256, 0, stream>>>(wih, wihb, n4);
        n4 = L_ * D_ * H_ / 4;
        w2bf_kernel<<<(n4 + 255) / 256, 256, 0, stream>>>(wfc, wfcb, n4);
        n4 = L_ * DI_ * D_ / 4;
        w2bf_kernel<<<(n4 + 255) / 256, 256, 0, stream>>>(w1, w1b, n4);
        n4 = L_ * D_ * DI_ / 4;
        w2bf_kernel<<<(n4 + 255) / 256, 256, 0, stream>>>(w2, w2b, n4);
    }

    hipMemcpyAsync(xcur, src, (size_t)NROW * D_ * sizeof(float),
                   hipMemcpyDeviceToDevice, stream);

    for (int l = 0; l < L_; l++) {
        // --- janossy layer ---
        ln_kernel<<<NROW, 256, 0, stream>>>(xcur, ln1_g + (size_t)l * D_,
                                            ln1_b + (size_t)l * D_, lnb);
        mfma_gemm<0, 0, 0, 2><<<dim3(G4H / 64, NROW / 64), 256, 0, stream>>>(
            lnb, wihb + (size_t)l * G4H * D_, nullptr, nullptr, xg5, NROW, G4H, D_);
        lstm_v4_kernel<<<dim3(S_, 2), 256, 0, stream>>>(
            xg5, whh + (size_t)l * G4H * H_, hb);
        mfma_gemm<0, 0, 1, 0><<<dim3(D_ / 64, NROW / 64), 256, 0, stream>>>(
            hb, wfcb + (size_t)l * D_ * H_, nullptr, xcur, xcur, NROW, D_, H_);
        // --- FFN ---
        ln_kernel<<<NROW, 256, 0, stream>>>(xcur, ln2_g + (size_t)l * D_,
                                            ln2_b + (size_t)l * D_, lnb);
        mfma_gemm<1, 1, 0, 1><<<dim3(DI_ / 64, NROW / 64), 256, 0, stream>>>(
            lnb, w1b + (size_t)l * DI_ * D_, b1 + (size_t)l * DI_, nullptr, f1, NROW, DI_, D_);
        mfma_gemm<1, 0, 1, 0><<<dim3(D_ / 64, NROW / 64), 256, 0, stream>>>(
            f1, w2b + (size_t)l * D_ * DI_, b2 + (size_t)l * D_, xcur, xcur, NROW, D_, DI_);
    }
    final_kernel<<<NROW, 256, 0, stream>>>(xcur, lnf_g, lnf_b, wprj, out);
}

// Round 9
// 713.957 us; speedup vs baseline: 2.1038x; 1.0034x over previous
//
#include <hip/hip_runtime.h>
#include <hip/hip_bf16.h>

#define B_ 16
#define S_ 80
#define D_ 512
#define H_ 64
#define DI_ 2048
#define L_ 6
#define G4H 256            // 4*H
#define NROW (B_ * S_)     // 1280 rows = (b, s)
#define EPS_ 1e-6f

typedef __attribute__((ext_vector_type(8))) short short8;
typedef __attribute__((ext_vector_type(4))) float f32x4;

// ---------------- math helpers ----------------
__device__ __forceinline__ float sigmoidf_(float x) {
    return __fdividef(1.0f, 1.0f + __expf(-x));
}
__device__ __forceinline__ float tanh_(float x) {
    return __fdividef(2.0f, 1.0f + __expf(-2.0f * x)) - 1.0f;
}
__device__ __forceinline__ short f2bf(float f) {
    __hip_bfloat16 h = __float2bfloat16(f);   // RNE
    return *reinterpret_cast<short*>(&h);
}

// Barrier that waits only on LDS traffic (lgkmcnt), NOT on in-flight global loads
// (vmcnt). __syncthreads() emits s_waitcnt vmcnt(0) lgkmcnt(0) and drains wave-
// private register prefetches every iteration — the m97 barrier-drain pathology.
// All cross-wave data here moves through LDS, so lgkmcnt(0) is sufficient.
__device__ __forceinline__ void lds_barrier() {
    __asm__ volatile("s_waitcnt lgkmcnt(0)\n\ts_barrier" ::: "memory");
}

// ---------------- fp32 -> bf16 weight conversion (once per launch) ----------------
__global__ __launch_bounds__(256)
void w2bf_kernel(const float* __restrict__ s, __hip_bfloat16* __restrict__ d, int n4) {
    int i = blockIdx.x * 256 + threadIdx.x;
    if (i < n4) {
        float4 v = reinterpret_cast<const float4*>(s)[i];
        short4 o;
        o.x = f2bf(v.x); o.y = f2bf(v.y); o.z = f2bf(v.z); o.w = f2bf(v.w);
        reinterpret_cast<short4*>(d)[i] = o;
    }
}

// ---------------- LayerNorm: one block per row, shuffle reduce (2 barriers) ----------------
__global__ __launch_bounds__(256)
void ln_kernel(const float* __restrict__ x, const float* __restrict__ g,
               const float* __restrict__ b, __hip_bfloat16* __restrict__ out) {
    int row = blockIdx.x;
    int t = threadIdx.x;
    const float* xr = x + (size_t)row * D_;
    float v0 = xr[t], v1 = xr[t + 256];
    __shared__ float ws4[4], qs4[4];
    float s = v0 + v1;
    #pragma unroll
    for (int o = 32; o > 0; o >>= 1) s += __shfl_down(s, o);
    if ((t & 63) == 0) ws4[t >> 6] = s;
    __syncthreads();
    float m = (ws4[0] + ws4[1] + ws4[2] + ws4[3]) * (1.0f / (float)D_);
    float d0 = v0 - m, d1 = v1 - m;
    float q = d0 * d0 + d1 * d1;
    #pragma unroll
    for (int o = 32; o > 0; o >>= 1) q += __shfl_down(q, o);
    if ((t & 63) == 0) qs4[t >> 6] = q;
    __syncthreads();
    float rs = rsqrtf((qs4[0] + qs4[1] + qs4[2] + qs4[3]) * (1.0f / (float)D_) + EPS_);
    __hip_bfloat16* orow = out + (size_t)row * D_;
    orow[t]       = __float2bfloat16(d0 * rs * g[t]       + b[t]);
    orow[t + 256] = __float2bfloat16(d1 * rs * g[t + 256] + b[t + 256]);
}

// ---------------- bf16 MFMA GEMM: C[M,N] = A[M,K] @ W[N,K]^T (+bias)(+relu)(+res) -----------
// A and W both bf16 row-major (weights pre-converted). BK=64, register-prefetch
// pipeline. lds_barrier (lgkmcnt-only) keeps the next tile's global loads in flight
// across the barrier; their vmcnt wait happens at the ds_write that consumes them,
// after the full compute phase has covered the latency.
// OUT_MODE: 0 = fp32 row-major, 1 = bf16 row-major,
//           2 = fp32 xg5 layout [s][half][gate][unit64][slot8]  (half=b>>3, slot=b&7)
template<int WITH_BIAS, int WITH_RELU, int WITH_RES, int OUT_MODE>
__global__ __launch_bounds__(256)
void mfma_gemm(const __hip_bfloat16* __restrict__ A, const __hip_bfloat16* __restrict__ W,
               const float* __restrict__ bias, const float* __restrict__ res,
               void* __restrict__ C, int M, int N, int K) {
    const int LDT = 72;  // LDS row stride in shorts (144B rows, 16B-aligned)
    __shared__ short As[64 * LDT];
    __shared__ short Ws[64 * LDT];

    int tid  = threadIdx.x;
    int wave = tid >> 6, lane = tid & 63;
    int quad = lane >> 4, l16 = lane & 15;
    int m_off = (wave >> 1) * 32, n_off = (wave & 1) * 32;
    int m0 = blockIdx.y * 64, n0 = blockIdx.x * 64;

    int r = tid >> 2, c = tid & 3;           // staging: row 0..63, 16-elem chunk 0..3
    const short* Ag = reinterpret_cast<const short*>(A);
    const short* Wg = reinterpret_cast<const short*>(W);

    f32x4 acc00 = {0.f,0.f,0.f,0.f}, acc01 = acc00, acc10 = acc00, acc11 = acc00;

    short8 avA[2], avW[2];                   // staged tile in registers
    auto load_tile = [&](int k0) {
        const short* arow = &Ag[(size_t)(m0 + r) * K + k0 + c * 16];
        avA[0] = *reinterpret_cast<const short8*>(arow);
        avA[1] = *reinterpret_cast<const short8*>(arow + 8);
        const short* wrow = &Wg[(size_t)(n0 + r) * K + k0 + c * 16];
        avW[0] = *reinterpret_cast<const short8*>(wrow);
        avW[1] = *reinterpret_cast<const short8*>(wrow + 8);
    };

    load_tile(0);                            // prologue
    for (int k0 = 0; k0 < K; k0 += 64) {
        lds_barrier();                       // prev frag reads done; vmem stays in flight
        *reinterpret_cast<short8*>(&As[r * LDT + c * 16])     = avA[0];
        *reinterpret_cast<short8*>(&As[r * LDT + c * 16 + 8]) = avA[1];
        *reinterpret_cast<short8*>(&Ws[r * LDT + c * 16])     = avW[0];
        *reinterpret_cast<short8*>(&Ws[r * LDT + c * 16 + 8]) = avW[1];
        lds_barrier();
        if (k0 + 64 < K) load_tile(k0 + 64); // issue next loads; consumed next iteration

        #pragma unroll
        for (int kc = 0; kc < 2; kc++) {
            short8 a0 = *reinterpret_cast<const short8*>(&As[(m_off + l16) * LDT + kc * 32 + quad * 8]);
            short8 a1 = *reinterpret_cast<const short8*>(&As[(m_off + 16 + l16) * LDT + kc * 32 + quad * 8]);
            short8 b0 = *reinterpret_cast<const short8*>(&Ws[(n_off + l16) * LDT + kc * 32 + quad * 8]);
            short8 b1 = *reinterpret_cast<const short8*>(&Ws[(n_off + 16 + l16) * LDT + kc * 32 + quad * 8]);
            acc00 = __builtin_amdgcn_mfma_f32_16x16x32_bf16(a0, b0, acc00, 0, 0, 0);
            acc01 = __builtin_amdgcn_mfma_f32_16x16x32_bf16(a0, b1, acc01, 0, 0, 0);
            acc10 = __builtin_amdgcn_mfma_f32_16x16x32_bf16(a1, b0, acc10, 0, 0, 0);
            acc11 = __builtin_amdgcn_mfma_f32_16x16x32_bf16(a1, b1, acc11, 0, 0, 0);
        }
    }

    f32x4 accs[2][2] = {{acc00, acc01}, {acc10, acc11}};
    #pragma unroll
    for (int fi = 0; fi < 2; fi++) {
        #pragma unroll
        for (int fj = 0; fj < 2; fj++) {
            int coln = n0 + n_off + fj * 16 + l16;
            float bv = WITH_BIAS ? bias[coln] : 0.0f;
            #pragma unroll
            for (int rr = 0; rr < 4; rr++) {
                int rowm = m0 + m_off + fi * 16 + quad * 4 + rr;
                float v = accs[fi][fj][rr];
                if (WITH_BIAS) v += bv;
                if (WITH_RELU) v = fmaxf(v, 0.0f);
                if (WITH_RES)  v += res[(size_t)rowm * N + coln];
                if (OUT_MODE == 0) {
                    reinterpret_cast<float*>(C)[(size_t)rowm * N + coln] = v;
                } else if (OUT_MODE == 1) {
                    reinterpret_cast<__hip_bfloat16*>(C)[(size_t)rowm * N + coln] = __float2bfloat16(v);
                } else {
                    int b_ = rowm / S_;
                    int s_ = rowm - b_ * S_;
                    int gate = coln >> 6, u = coln & 63;
                    int half = b_ >> 3, slot = b_ & 7;
                    reinterpret_cast<float*>(C)[
                        ((((size_t)(s_ * 2 + half) * 4 + gate) * 64 + u) << 3) + slot] = v;
                }
            }
        }
    }
}

// ---------------- MFMA LSTM v4: fp32 C-init from xg, M=8, 1 lgkm-barrier/step ----------------
// Grid (80,2): block = (output position i, batch half bh), 4 waves. Batches placed at
// C-rows {0,1,4,5,...} so every lane owns exactly 2 states. Per gate per step:
//   acc = {xg0, xg1, ...};  acc = mfma(h0, Whh0, acc);  acc = mfma(h1, Whh1, acc)
// xg: ONE coalesced float2 per gate, prefetched 1 step ahead into registers. The
// lds_barrier (lgkmcnt-only) does NOT drain those loads — they stay in flight across
// the barrier and wait fine-grained at the acc-init that consumes them.
__global__ __launch_bounds__(256)
void lstm_v4_kernel(const float* __restrict__ xg5,  // [S][2][4][64][8] fp32
                    const float* __restrict__ whh,  // [4H, H] fp32
                    __hip_bfloat16* __restrict__ hlast) {  // [B, S, H]
    const int i    = blockIdx.x;      // output position 0..79
    const int bh   = blockIdx.y;      // batch half 0..1
    const int tid  = threadIdx.x;
    const int wave = tid >> 6, lane = tid & 63;
    const int quad = lane >> 4, l16 = lane & 15;
    const int unit = wave * 16 + l16; // hidden unit owned on the C side

    // Whh B-fragments (bf16), one-time. Tile g: col n = l16 <-> whh row g*64 + unit.
    short8 bfrag[4][2];
    #pragma unroll
    for (int g = 0; g < 4; g++) {
        const float* wr = &whh[(size_t)(g * 64 + unit) * H_];
        #pragma unroll
        for (int kc = 0; kc < 2; kc++) {
            float4 x0 = *(const float4*)(wr + kc * 32 + quad * 8);
            float4 x1 = *(const float4*)(wr + kc * 32 + quad * 8 + 4);
            short8 v;
            v[0] = f2bf(x0.x); v[1] = f2bf(x0.y); v[2] = f2bf(x0.z); v[3] = f2bf(x0.w);
            v[4] = f2bf(x1.x); v[5] = f2bf(x1.y); v[6] = f2bf(x1.z); v[7] = f2bf(x1.w);
            bfrag[g][kc] = v;
        }
    }

    // h in LDS, double-buffered by step parity; 72-short rows (144B, 16B-aligned)
    __shared__ __attribute__((aligned(16))) short hsh[2][16][72];
    for (int idx = tid; idx < 2 * 16 * 72; idx += 256)
        reinterpret_cast<short*>(hsh)[idx] = 0;

    float cst[2] = {0.f, 0.f};
    float hvv[2] = {0.f, 0.f};

    // xg float2 addresses: (((s*2+bh)*4 + g)*64 + unit)*8 + quad*2
    size_t xoff[4];
    #pragma unroll
    for (int g = 0; g < 4; g++)
        xoff[g] = ((((size_t)bh * 4 + g) * 64 + unit) << 3) + quad * 2;

    float2 xv[4];
    {
        int s0 = (0 == i) ? (S_ - 1) : 0;
        #pragma unroll
        for (int g = 0; g < 4; g++)
            xv[g] = *reinterpret_cast<const float2*>(&xg5[(size_t)s0 * 4096 + xoff[g]]);
    }

    lds_barrier();  // LDS zero-init visible

    for (int t = 0; t < S_; t++) {
        const int pb = t & 1;
        short8 af0 = *reinterpret_cast<const short8*>(&hsh[pb][l16][quad * 8]);
        short8 af1 = *reinterpret_cast<const short8*>(&hsh[pb][l16][32 + quad * 8]);

        f32x4 acc[4];
        #pragma unroll
        for (int g = 0; g < 4; g++) {
            f32x4 a = {xv[g].x, xv[g].y, xv[g].x, xv[g].y};  // rows 2,3 unused
            acc[g] = a;
        }

        // prefetch next step's xg (xv just consumed; stays in flight across the barrier)
        if (t + 1 < S_) {
            int tn = t + 1;
            int sn = (tn == i) ? (S_ - 1) : ((tn == S_ - 1) ? i : tn);
            #pragma unroll
            for (int g = 0; g < 4; g++)
                xv[g] = *reinterpret_cast<const float2*>(&xg5[(size_t)sn * 4096 + xoff[g]]);
        }

        #pragma unroll
        for (int g = 0; g < 4; g++) {
            acc[g] = __builtin_amdgcn_mfma_f32_16x16x32_bf16(af0, bfrag[g][0], acc[g], 0, 0, 0);
            acc[g] = __builtin_amdgcn_mfma_f32_16x16x32_bf16(af1, bfrag[g][1], acc[g], 0, 0, 0);
        }

        #pragma unroll
        for (int r = 0; r < 2; r++) {
            float ig = sigmoidf_(acc[0][r]);
            float fg = sigmoidf_(acc[1][r]);
            float gg = tanh_(acc[2][r]);
            float og = sigmoidf_(acc[3][r]);
            float cc = fg * cst[r] + ig * gg;
            cst[r] = cc;
            float h = og * tanh_(cc);
            hvv[r] = h;
            hsh[pb ^ 1][quad * 4 + r][unit] = f2bf(h);
        }
        lds_barrier();
    }

    #pragma unroll
    for (int r = 0; r < 2; r++) {
        int b = bh * 8 + quad * 2 + r;
        hlast[((size_t)b * S_ + i) * H_ + unit] = __float2bfloat16(hvv[r]);
    }
}

// ---------------- final LN + projection to one logit per row ----------------
__global__ __launch_bounds__(256)
void final_kernel(const float* __restrict__ x, const float* __restrict__ g,
                  const float* __restrict__ b, const float* __restrict__ wprj,
                  float* __restrict__ out) {
    int row = blockIdx.x;
    int t = threadIdx.x;
    const float* xr = x + (size_t)row * D_;
    float v0 = xr[t], v1 = xr[t + 256];
    __shared__ float red[256];
    red[t] = v0 + v1;
    __syncthreads();
    for (int o = 128; o > 0; o >>= 1) { if (t < o) red[t] += red[t + o]; __syncthreads(); }
    float m = red[0] * (1.0f / (float)D_);
    __syncthreads();
    float d0 = v0 - m, d1 = v1 - m;
    red[t] = d0 * d0 + d1 * d1;
    __syncthreads();
    for (int o = 128; o > 0; o >>= 1) { if (t < o) red[t] += red[t + o]; __syncthreads(); }
    float rs = rsqrtf(red[0] * (1.0f / (float)D_) + EPS_);
    __syncthreads();
    float y0 = (d0 * rs * g[t] + b[t]) * wprj[t];
    float y1 = (d1 * rs * g[t + 256] + b[t + 256]) * wprj[t + 256];
    red[t] = y0 + y1;
    __syncthreads();
    for (int o = 128; o > 0; o >>= 1) { if (t < o) red[t] += red[t + o]; __syncthreads(); }
    if (t == 0) out[row] = red[0];
}

// ---------------- host ----------------
extern "C" void kernel_launch(void* const* d_in, const int* in_sizes, int n_in,
                              void* d_out, int out_size, void* d_ws, size_t ws_size,
                              hipStream_t stream) {
    const float* src   = (const float*)d_in[0];
    const float* ln1_g = (const float*)d_in[2];
    const float* ln1_b = (const float*)d_in[3];
    const float* wih   = (const float*)d_in[4];   // [L, 4H, D]
    const float* whh   = (const float*)d_in[5];   // [L, 4H, H]
    const float* wfc   = (const float*)d_in[6];   // [L, D, H]
    const float* ln2_g = (const float*)d_in[7];
    const float* ln2_b = (const float*)d_in[8];
    const float* w1    = (const float*)d_in[9];   // [L, DI, D]
    const float* b1    = (const float*)d_in[10];  // [L, DI]
    const float* w2    = (const float*)d_in[11];  // [L, D, DI]
    const float* b2    = (const float*)d_in[12];  // [L, D]
    const float* lnf_g = (const float*)d_in[13];
    const float* lnf_b = (const float*)d_in[14];
    const float* wprj  = (const float*)d_in[15];  // [1, D]
    float* out = (float*)d_out;

    char* ws = (char*)d_ws;
    float* xcur = (float*)ws;                       ws += (size_t)NROW * D_  * 4;  // fp32 residual stream
    __hip_bfloat16* lnb = (__hip_bfloat16*)ws;      ws += (size_t)NROW * D_  * 2;  // LN output (bf16 A-operand)
    float* xg5  = (float*)ws;                       ws += (size_t)S_ * 4096  * 4;  // gate proj fp32 [s][2][4][64][8]
    __hip_bfloat16* hb  = (__hip_bfloat16*)ws;      ws += (size_t)NROW * H_  * 2;  // LSTM h (bf16 A-operand)
    __hip_bfloat16* f1  = (__hip_bfloat16*)ws;      ws += (size_t)NROW * DI_ * 2;  // FFN hidden (bf16 A-operand)
    __hip_bfloat16* wihb = (__hip_bfloat16*)ws;     ws += (size_t)L_ * G4H * D_ * 2;
    __hip_bfloat16* wfcb = (__hip_bfloat16*)ws;     ws += (size_t)L_ * D_ * H_ * 2;
    __hip_bfloat16* w1b  = (__hip_bfloat16*)ws;     ws += (size_t)L_ * DI_ * D_ * 2;
    __hip_bfloat16* w2b  = (__hip_bfloat16*)ws;     ws += (size_t)L_ * D_ * DI_ * 2;

    // one-time (per launch) weight conversions to bf16
    {
        int n4;
        n4 = L_ * G4H * D_ / 4;
        w2bf_kernel<<<(n4 + 255) / 256, 256, 0, stream>>>(wih, wihb, n4);
        n4 = L_ * D_ * H_ / 4;
        w2bf_kernel<<<(n4 + 255) / 256, 256, 0, stream>>>(wfc, wfcb, n4);
        n4 = L_ * DI_ * D_ / 4;
        w2bf_kernel<<<(n4 + 255) / 256, 256, 0, stream>>>(w1, w1b, n4);
        n4 = L_ * D_ * DI_ / 4;
        w2bf_kernel<<<(n4 + 255) / 256, 256, 0, stream>>>(w2, w2b, n4);
    }

    hipMemcpyAsync(xcur, src, (size_t)NROW * D_ * sizeof(float),
                   hipMemcpyDeviceToDevice, stream);

    for (int l = 0; l < L_; l++) {
        // --- janossy layer ---
        ln_kernel<<<NROW, 256, 0, stream>>>(xcur, ln1_g + (size_t)l * D_,
                                            ln1_b + (size_t)l * D_, lnb);
        mfma_gemm<0, 0, 0, 2><<<dim3(G4H / 64, NROW / 64), 256, 0, stream>>>(
            lnb, wihb + (size_t)l * G4H * D_, nullptr, nullptr, xg5, NROW, G4H, D_);
        lstm_v4_kernel<<<dim3(S_, 2), 256, 0, stream>>>(
            xg5, whh + (size_t)l * G4H * H_, hb);
        mfma_gemm<0, 0, 1, 0><<<dim3(D_ / 64, NROW / 64), 256, 0, stream>>>(
            hb, wfcb + (size_t)l * D_ * H_, nullptr, xcur, xcur, NROW, D_, H_);
        // --- FFN ---
        ln_kernel<<<NROW, 256, 0, stream>>>(xcur, ln2_g + (size_t)l * D_,
                                            ln2_b + (size_t)l * D_, lnb);
        mfma_gemm<1, 1, 0, 1><<<dim3(DI_ / 64, NROW / 64), 256, 0, stream>>>(
            lnb, w1b + (size_t)l * DI_ * D_, b1 + (size_t)l * DI_, nullptr, f1, NROW, DI_, D_);
        mfma_gemm<1, 0, 1, 0><<<dim3(D_ / 64, NROW / 64), 256, 0, stream>>>(
            f1, w2b + (size_t)l * D_ * DI_, b2 + (size_t)l * D_, xcur, xcur, NROW, D_, DI_);
    }
    final_kernel<<<NROW, 256, 0, stream>>>(xcur, lnf_g, lnf_b, wprj, out);
}